// Round 2
// baseline (999.266 us; speedup 1.0000x reference)
//
#include <hip/hip_runtime.h>

// Axial attention for N=16, C=64, H=W=256.
// K1: h (NCHW f32) -> hT (N,H,W,C) bf16            [ws 0..128MB)
// K2: row attention (per (n,w), attend over H) -> attnOut (N,H,W,C) bf16 [ws 128..256MB)
// K3: col attention (per (n,y), attend over W) + attnOut + h -> out (NCHW f32)
//
// softmax(q.k^T) == softmax( X*(At/16)*X^T + w[g]/16 ), At = Wq^T Wk (we use At^T = Wk^T Wq
// as the A operand), w[g] = X[g].(Wk^T bq). V bias added in epilogue (softmax rows sum to 1).
//
// "Virtual tile" trick: scores are computed as S^T tiles via mfma(A = X rows, B = q~ frags),
// with A-tile rows permuted as g = 32*kt + 8*l4 + 4*j + r so that each lane's score outputs
// are exactly the k-elements (k = 8*l4 + e) of its own PV A-fragment -> P repacks IN-LANE
// (no LDS staging, no shuffles). Same permutation baked into the AtF scatter makes q~
// repack in-lane as well. All operand placements use one consistent k-map, so correctness
// is independent of the true HW k-ordering (position-pairing argument).

typedef unsigned short u16t;
typedef __bf16 bf16x8 __attribute__((ext_vector_type(8)));
typedef float  f32x4  __attribute__((ext_vector_type(4)));
typedef u16t   us8    __attribute__((ext_vector_type(8)));
typedef u16t   us4    __attribute__((ext_vector_type(4)));
typedef unsigned uu4  __attribute__((ext_vector_type(4)));

#define DEVINL __device__ __forceinline__

DEVINL u16t f2bf(float f){
    unsigned u = __builtin_bit_cast(unsigned, f);
    u += 0x7fffu + ((u >> 16) & 1u);          // round-to-nearest-even
    return (u16t)(u >> 16);
}
DEVINL float bf2f(u16t h){
    unsigned u = ((unsigned)h) << 16;
    return __builtin_bit_cast(float, u);
}
DEVINL unsigned pk2(float lo, float hi){
    return ((unsigned)f2bf(hi) << 16) | (unsigned)f2bf(lo);
}
DEVINL f32x4 mfma16(bf16x8 a, bf16x8 b, f32x4 c){
    return __builtin_amdgcn_mfma_f32_16x16x32_bf16(a, b, c, 0, 0, 0);
}
// Xs swizzle: 2-term XOR spreads banks for both natural-row and virtual-row frag reads.
DEVINL int xswz(int row, int chunk){
    return row*128 + ((chunk << 4) ^ (((row & 7) ^ ((row >> 2) & 7)) << 4));
}

// ---------------- K1: transpose h (N,C,H,W) f32 -> hT (N,H,W,C) bf16 ----------------
__global__ __launch_bounds__(256) void transpose_kernel(const float* __restrict__ h,
                                                        u16t* __restrict__ hT){
    __shared__ float tile[64][257];
    const int bid = blockIdx.x;          // n*256 + y
    const int n = bid >> 8, y = bid & 255;
    const int tid = threadIdx.x;
    {
        const int c = tid >> 2, w0 = (tid & 3) * 64;
        const int base = ((n * 64 + c) * 256 + y) * 256 + w0;
        #pragma unroll
        for (int i = 0; i < 16; ++i){
            f32x4 v = *(const f32x4*)(h + base + i * 4);
            tile[c][w0 + i*4 + 0] = v[0];
            tile[c][w0 + i*4 + 1] = v[1];
            tile[c][w0 + i*4 + 2] = v[2];
            tile[c][w0 + i*4 + 3] = v[3];
        }
    }
    __syncthreads();
    #pragma unroll
    for (int j = 0; j < 4; ++j){
        const int task = tid + 256 * j;
        const int w = task >> 2, c0 = (task & 3) * 16;
        us8 o0, o1;
        #pragma unroll
        for (int e = 0; e < 8; ++e) o0[e] = f2bf(tile[c0 + e][w]);
        #pragma unroll
        for (int e = 0; e < 8; ++e) o1[e] = f2bf(tile[c0 + 8 + e][w]);
        const int ob = ((n * 256 + y) * 256 + w) * 64 + c0;
        *(us8*)(hT + ob)     = o0;
        *(us8*)(hT + ob + 8) = o1;
    }
}

// ---------------- K2/K3: attention. COL=0: row attn -> attnOut. COL=1: col attn + combine -> out.
template<int COL>
__global__ __launch_bounds__(512, 4) void attn_kernel(
    const u16t* __restrict__ hT,
    const float* __restrict__ wq, const float* __restrict__ bq,
    const float* __restrict__ wk, const float* __restrict__ wvw,
    const float* __restrict__ bvp,
    u16t* __restrict__ attnOut,
    const float* __restrict__ hsrc, float* __restrict__ outp)
{
    __shared__ __align__(16) u16t Xs[16384];    // X 256x64 bf16, swizzled rows of 128B
    __shared__ __align__(16) u16t VtF[16384];   // V as PV B-frags [f=nt*8+kt][lane][e]; reused as OutS
    __shared__ __align__(16) u16t AtF[4096];    // At^T/16 as A-frags (virtual-row-permuted)
    __shared__ __align__(16) float w16s[256];
    __shared__ float wkbqs[64];
    __shared__ float bvs[64];

    const int tid  = threadIdx.x;
    const int lane = tid & 63;
    const int wv   = tid >> 6;
    const int bid  = blockIdx.x;
    const int n    = bid >> 8;
    const int idx  = bid & 255;               // w (row mode) or y (col mode)
    const int l15  = lane & 15;
    const int l4   = lane >> 4;
    const int nbase = n * 4194304;            // n*H*W*C

    // ---- phase 0a: stage X into LDS
    #pragma unroll
    for (int pass = 0; pass < 4; ++pass){
        const int i = pass * 512 + tid;
        const int row = i >> 3, cc = i & 7;
        const int goff = COL ? (nbase + idx * 16384 + row * 64 + cc * 8)
                             : (nbase + row * 16384 + idx * 64 + cc * 8);
        us8 v = *(const us8*)(hT + goff);
        *(us8*)((char*)Xs + xswz(row, cc)) = v;
    }

    // ---- phase 0b: At^T/16 = (Wk^T Wq)/16 -> AtF in A-frag layout with virtual-row perm
    {
        const int mtA = wv >> 1;
        us8 aku[2];
        #pragma unroll
        for (int kt = 0; kt < 2; ++kt)
            #pragma unroll
            for (int e = 0; e < 8; ++e)
                aku[kt][e] = f2bf(wk[(kt*32 + l4*8 + e)*64 + mtA*16 + l15]);
        #pragma unroll
        for (int t2 = 0; t2 < 2; ++t2){
            const int ntA = (2*wv + t2) & 3;
            us8 bqu[2];
            #pragma unroll
            for (int kt = 0; kt < 2; ++kt)
                #pragma unroll
                for (int e = 0; e < 8; ++e)
                    bqu[kt][e] = f2bf(wq[(kt*32 + l4*8 + e)*64 + ntA*16 + l15]);
            f32x4 acc = {0.f,0.f,0.f,0.f};
            acc = mfma16(__builtin_bit_cast(bf16x8, aku[0]), __builtin_bit_cast(bf16x8, bqu[0]), acc);
            acc = mfma16(__builtin_bit_cast(bf16x8, aku[1]), __builtin_bit_cast(bf16x8, bqu[1]), acc);
            #pragma unroll
            for (int r = 0; r < 4; ++r){
                const int cp = mtA*16 + 4*l4 + r;          // row of At^T (= c')
                const int cc = ntA*16 + l15;               // col (= c, the k-dim)
                const int vtq  = 2*(cp>>5) + ((cp>>2)&1);
                const int mrow = 4*((cp>>3)&3) + (cp&3);
                const int f    = vtq*2 + (cc>>5);
                AtF[(f*64 + ((cc>>3)&3)*16 + mrow)*8 + (cc&7)] = f2bf(acc[r] * 0.0625f);
            }
        }
    }
    if (tid < 64){
        float acc = 0.f;
        for (int o = 0; o < 64; ++o) acc += wk[o*64 + tid] * bq[o];
        wkbqs[tid] = acc;
        bvs[tid] = bvp[tid];
    }
    __syncthreads();

    // ---- phase 1: V = X @ Wv^T scattered directly into PV B-frag layout; w16s
    {
        const int ct = wv >> 1;
        bf16x8 awv[2];
        #pragma unroll
        for (int ktc = 0; ktc < 2; ++ktc){
            const float* wp = wvw + (ct*16 + l15)*64 + ktc*32 + l4*8;
            f32x4 v0 = *(const f32x4*)wp;
            f32x4 v1 = *(const f32x4*)(wp + 4);
            us8 u;
            #pragma unroll
            for (int e = 0; e < 4; ++e){ u[e] = f2bf(v0[e]); u[4+e] = f2bf(v1[e]); }
            awv[ktc] = __builtin_bit_cast(bf16x8, u);
        }
        #pragma unroll
        for (int t = 0; t < 8; ++t){
            const int gt = (wv & 1)*8 + t;
            bf16x8 bx0 = *(const bf16x8*)((const char*)Xs + xswz(gt*16 + l15, l4));
            bf16x8 bx1 = *(const bf16x8*)((const char*)Xs + xswz(gt*16 + l15, 4 + l4));
            f32x4 z = {0.f,0.f,0.f,0.f};
            z = mfma16(awv[0], bx0, z);
            z = mfma16(awv[1], bx1, z);
            // produced: c = ct*16+4*l4+rr, g = gt*16+l15 -> frag (f = (c>>4)*8+(g>>5))
            const int fidx = ct*8 + (gt>>1);
            const int lt   = (2*(gt&1) + (l15>>3))*16 + 4*l4;
            const int e    = l15 & 7;
            #pragma unroll
            for (int rr = 0; rr < 4; ++rr)
                VtF[(fidx*64 + lt + rr)*8 + e] = f2bf(z[rr]);
        }
    }
    if (tid < 256){
        float acc = 0.f;
        #pragma unroll
        for (int cc = 0; cc < 8; ++cc){
            us8 xv = *(const us8*)((const char*)Xs + xswz(tid, cc));
            #pragma unroll
            for (int e = 0; e < 8; ++e) acc += bf2f(xv[e]) * wkbqs[cc*8 + e];
        }
        w16s[tid] = acc * 0.0625f;
    }
    __syncthreads();

    // ---- phase 2: per-wave attention, qrow tiles mt = 2*wv + mi
    const int rowoff = 8*(l15>>2) + (l15&3);   // virtual-tile per-lane row offset
    unsigned ovp[2][4][2];                      // COL: packed (out+bias+rowattn) pairs

    #pragma unroll
    for (int mi = 0; mi < 2; ++mi){
        const int mt = wv*2 + mi;
        // q~^T tiles: mfma(A=AtF, B=X rows of this q-tile); values land in-lane at
        // c' = 32*kt2 + 8*l4 + 4*j + r thanks to the AtF virtual-row perm.
        bf16x8 xq0 = *(const bf16x8*)((const char*)Xs + xswz(mt*16 + l15, l4));
        bf16x8 xq1 = *(const bf16x8*)((const char*)Xs + xswz(mt*16 + l15, 4 + l4));
        f32x4 qa[4];
        #pragma unroll
        for (int vtq = 0; vtq < 4; ++vtq){
            bf16x8 a0 = *(const bf16x8*)(AtF + ((vtq*2 + 0)*64 + lane)*8);
            bf16x8 a1 = *(const bf16x8*)(AtF + ((vtq*2 + 1)*64 + lane)*8);
            f32x4 z = {0.f,0.f,0.f,0.f};
            z = mfma16(a0, xq0, z);
            qa[vtq] = mfma16(a1, xq1, z);
        }
        // in-lane repack -> q~ B-frags (k = 32*ktc + 8*l4 + e)
        uu4 qp0, qp1;
        #pragma unroll
        for (int e01 = 0; e01 < 4; ++e01){
            const int j = e01 >> 1, r0 = 2*(e01 & 1);
            qp0[e01] = pk2(qa[0*2 + j][r0], qa[0*2 + j][r0 + 1]);
            qp1[e01] = pk2(qa[1*2 + j][r0], qa[1*2 + j][r0 + 1]);
        }
        const bf16x8 qb0 = __builtin_bit_cast(bf16x8, qp0);
        const bf16x8 qb1 = __builtin_bit_cast(bf16x8, qp1);

        // scores S^T via virtual A-tiles: lane holds g = 32*(vt>>1) + 8*l4 + 4*(vt&1) + r
        f32x4 sv[16];
        #pragma unroll
        for (int vt = 0; vt < 16; ++vt){
            const int rbase = 32*(vt>>1) + 4*(vt&1);
            const int row = rbase + rowoff;
            bf16x8 xa0 = *(const bf16x8*)((const char*)Xs + xswz(row, l4));
            bf16x8 xa1 = *(const bf16x8*)((const char*)Xs + xswz(row, 4 + l4));
            f32x4 z = {0.f,0.f,0.f,0.f};
            z = mfma16(xa0, qb0, z);
            z = mfma16(xa1, qb1, z);
            f32x4 wg = *(const f32x4*)&w16s[rbase + 8*l4];
            #pragma unroll
            for (int r = 0; r < 4; ++r) sv[vt][r] = z[r] + wg[r];
        }
        // softmax: all 64 in-lane values belong to qrow = mt*16+l15; reduce across l4 (xor 16,32)
        f32x4 m4 = sv[0];
        #pragma unroll
        for (int vt = 1; vt < 16; ++vt)
            #pragma unroll
            for (int r = 0; r < 4; ++r) m4[r] = fmaxf(m4[r], sv[vt][r]);
        float mx = fmaxf(fmaxf(m4[0], m4[1]), fmaxf(m4[2], m4[3]));
        mx = fmaxf(mx, __shfl_xor(mx, 16));
        mx = fmaxf(mx, __shfl_xor(mx, 32));
        f32x4 s4 = {0.f,0.f,0.f,0.f};
        #pragma unroll
        for (int vt = 0; vt < 16; ++vt){
            #pragma unroll
            for (int r = 0; r < 4; ++r){
                float p = __expf(sv[vt][r] - mx);
                sv[vt][r] = p;
                s4[r] += p;
            }
        }
        float sum = (s4[0] + s4[1]) + (s4[2] + s4[3]);
        sum += __shfl_xor(sum, 16);
        sum += __shfl_xor(sum, 32);
        const float rscl = 1.f / sum;

        // in-lane repack -> normalized P A-frags (k = 32*kt + 8*l4 + e)
        unsigned pk[8][4];
        #pragma unroll
        for (int kt = 0; kt < 8; ++kt)
            #pragma unroll
            for (int e01 = 0; e01 < 4; ++e01){
                const int j = e01 >> 1, r0 = 2*(e01 & 1);
                pk[kt][e01] = pk2(sv[2*kt + j][r0] * rscl, sv[2*kt + j][r0 + 1] * rscl);
            }

        // PV: out[qrow][c] += P * V
        f32x4 po[4] = {{0.f,0.f,0.f,0.f},{0.f,0.f,0.f,0.f},{0.f,0.f,0.f,0.f},{0.f,0.f,0.f,0.f}};
        #pragma unroll
        for (int kt = 0; kt < 8; ++kt){
            uu4 t; t[0] = pk[kt][0]; t[1] = pk[kt][1]; t[2] = pk[kt][2]; t[3] = pk[kt][3];
            const bf16x8 pa = __builtin_bit_cast(bf16x8, t);
            #pragma unroll
            for (int nt = 0; nt < 4; ++nt){
                const bf16x8 vb = *(const bf16x8*)(VtF + ((nt*8 + kt)*64 + lane)*8);
                po[nt] = mfma16(pa, vb, po[nt]);
            }
        }

        if (!COL){
            #pragma unroll
            for (int nt = 0; nt < 4; ++nt){
                const int c = nt*16 + l15;
                const float b = bvs[c];
                #pragma unroll
                for (int r = 0; r < 4; ++r){
                    const int y = mt*16 + 4*l4 + r;
                    attnOut[nbase + y*16384 + idx*64 + c] = f2bf(po[nt][r] + b);
                }
            }
        } else {
            #pragma unroll
            for (int nt = 0; nt < 4; ++nt){
                const int c = nt*16 + l15;
                const float b = bvs[c];
                float vr[4];
                #pragma unroll
                for (int r = 0; r < 4; ++r){
                    const int w = mt*16 + 4*l4 + r;
                    vr[r] = po[nt][r] + b + bf2f(attnOut[nbase + idx*16384 + w*64 + c]);
                }
                ovp[mi][nt][0] = pk2(vr[0], vr[1]);
                ovp[mi][nt][1] = pk2(vr[2], vr[3]);
            }
        }
    }

    if (COL){
        __syncthreads();                      // all VtF frag reads done; reuse as OutS [c][w]
        u16t* OutS = VtF;
        #pragma unroll
        for (int mi = 0; mi < 2; ++mi){
            const int mt = wv*2 + mi;
            #pragma unroll
            for (int nt = 0; nt < 4; ++nt){
                const int c = nt*16 + l15;
                #pragma unroll
                for (int r01 = 0; r01 < 2; ++r01){
                    const int w0 = mt*16 + 4*l4 + 2*r01;
                    *(unsigned*)((char*)OutS + c*512 + ((w0*2) ^ ((c&7)<<4))) = ovp[mi][nt][r01];
                }
            }
        }
        __syncthreads();
        // final: out[n][c][y][w] = OutS[c][w] + h ; coalesced 1KB row writes
        #pragma unroll
        for (int k = 0; k < 8; ++k){
            const int c = wv*8 + k;
            us4 ov = *(const us4*)((const char*)OutS + c*512 + ((lane*8) ^ ((c&7)<<4)));
            const int gb = ((n*64 + c)*256 + idx)*256 + lane*4;
            f32x4 hres = *(const f32x4*)(hsrc + gb);
            f32x4 res;
            #pragma unroll
            for (int e = 0; e < 4; ++e) res[e] = hres[e] + bf2f(ov[e]);
            *(f32x4*)(outp + gb) = res;
        }
    }
}

extern "C" void kernel_launch(void* const* d_in, const int* in_sizes, int n_in,
                              void* d_out, int out_size, void* d_ws, size_t ws_size,
                              hipStream_t stream){
    const float* h   = (const float*)d_in[0];
    const float* wq  = (const float*)d_in[1];
    const float* bq  = (const float*)d_in[2];
    const float* wk  = (const float*)d_in[3];
    // d_in[4] = bk: cancels in softmax (row-constant), unused.
    const float* wvw = (const float*)d_in[5];
    const float* bv  = (const float*)d_in[6];
    float* out = (float*)d_out;

    u16t* hT      = (u16t*)d_ws;          // 67,108,864 bf16 = 128MB
    u16t* attnOut = hT + 67108864;        // 67,108,864 bf16 = 128MB

    transpose_kernel<<<4096, 256, 0, stream>>>(h, hT);
    attn_kernel<0><<<4096, 512, 0, stream>>>(hT, wq, bq, wk, wvw, bv, attnOut, h, out);
    attn_kernel<1><<<4096, 512, 0, stream>>>(hT, wq, bq, wk, wvw, bv, attnOut, h, out);
}